// Round 19
// baseline (410.163 us; speedup 1.0000x reference)
//
#include <hip/hip_runtime.h>
#include <hip/hip_bf16.h>

using bf16 = __hip_bfloat16;
typedef __attribute__((ext_vector_type(8))) short bf16x8;
typedef __attribute__((ext_vector_type(4))) float f32x4;
typedef __attribute__((ext_vector_type(16))) float f32x16;

#define LOG2E 1.4426950408889634f

__device__ inline short f2b(float f) {
  __hip_bfloat16 h = __float2bfloat16(f);
  return *reinterpret_cast<short*>(&h);
}
__device__ inline float b2f(short s) {
  unsigned int u = ((unsigned int)(unsigned short)s) << 16;
  float f;
  __builtin_memcpy(&f, &u, 4);
  return f;
}
// single-instruction packed f32x2 -> bf16x2 (RNE), lo = a, hi = b
__device__ inline unsigned cvtpk(float a, float b) {
  unsigned r;
  asm("v_cvt_pk_bf16_f32 %0, %1, %2" : "=v"(r) : "v"(a), "v"(b));
  return r;
}
// raw v_exp_f32: D = 2^S0 (no libm range checks)
__device__ inline float exp2_fast(float x) {
  float r;
  asm("v_exp_f32 %0, %1" : "=v"(r) : "v"(x));
  return r;
}

// ---------------- weight transpose + cast: in[K][N] f32 -> out[N][K] bf16 ----
__global__ __launch_bounds__(256) void transpose_cast_kernel(
    const float* __restrict__ in, bf16* __restrict__ out, int K, int N) {
  __shared__ float tile[32][33];
  int tx = threadIdx.x & 31;
  int ty = threadIdx.x >> 5;
  int n0 = blockIdx.x * 32, k0 = blockIdx.y * 32;
#pragma unroll
  for (int i = 0; i < 4; i++)
    tile[ty + i * 8][tx] = in[(size_t)(k0 + ty + i * 8) * N + n0 + tx];
  __syncthreads();
#pragma unroll
  for (int i = 0; i < 4; i++)
    out[(size_t)(n0 + ty + i * 8) * K + k0 + tx] =
        __float2bfloat16(tile[tx][ty + i * 8]);
}

// ---------------- LayerNorm (LN1): f32 in -> bf16 out -----------------------
__global__ __launch_bounds__(256) void ln_kernel(
    const float* __restrict__ x, const float* __restrict__ g,
    const float* __restrict__ b, bf16* __restrict__ out) {
  int row = blockIdx.x;
  const float4 v = ((const float4*)(x + (size_t)row * 1024))[threadIdx.x];
  float s = v.x + v.y + v.z + v.w;
  float ss = v.x * v.x + v.y * v.y + v.z * v.z + v.w * v.w;
#pragma unroll
  for (int off = 1; off < 64; off <<= 1) {
    s += __shfl_xor(s, off);
    ss += __shfl_xor(ss, off);
  }
  __shared__ float red[2][4];
  int w = threadIdx.x >> 6, lane = threadIdx.x & 63;
  if (lane == 0) { red[0][w] = s; red[1][w] = ss; }
  __syncthreads();
  s = red[0][0] + red[0][1] + red[0][2] + red[0][3];
  ss = red[1][0] + red[1][1] + red[1][2] + red[1][3];
  float mu = s * (1.0f / 1024.0f);
  float var = ss * (1.0f / 1024.0f) - mu * mu;
  float rstd = rsqrtf(var + 1e-5f);
  const float4 gv = ((const float4*)g)[threadIdx.x];
  const float4 bv = ((const float4*)b)[threadIdx.x];
  uint2 o2;
  o2.x = cvtpk((v.x - mu) * rstd * gv.x + bv.x, (v.y - mu) * rstd * gv.y + bv.y);
  o2.y = cvtpk((v.z - mu) * rstd * gv.z + bv.z, (v.w - mu) * rstd * gv.w + bv.w);
  ((uint2*)out)[(size_t)row * 256 + threadIdx.x] = o2;
}

// ---------------- fused: x1 = p0+p1 ; h2 = LN2(x1)  (bias+res already in p0)
__global__ __launch_bounds__(256) void fused_ln_kernel(
    const float* __restrict__ p0, const float* __restrict__ p1,
    const float* __restrict__ g, const float* __restrict__ bln,
    float* __restrict__ x1, bf16* __restrict__ h2) {
  int row = blockIdx.x;
  size_t base = (size_t)row * 256 + threadIdx.x;
  float4 a = ((const float4*)p0)[base];
  float4 c = ((const float4*)p1)[base];
  float4 v;
  v.x = a.x + c.x;
  v.y = a.y + c.y;
  v.z = a.z + c.z;
  v.w = a.w + c.w;
  ((float4*)x1)[base] = v;
  float s = v.x + v.y + v.z + v.w;
  float ss = v.x * v.x + v.y * v.y + v.z * v.z + v.w * v.w;
#pragma unroll
  for (int off = 1; off < 64; off <<= 1) {
    s += __shfl_xor(s, off);
    ss += __shfl_xor(ss, off);
  }
  __shared__ float red[2][4];
  int w = threadIdx.x >> 6, lane = threadIdx.x & 63;
  if (lane == 0) { red[0][w] = s; red[1][w] = ss; }
  __syncthreads();
  s = red[0][0] + red[0][1] + red[0][2] + red[0][3];
  ss = red[1][0] + red[1][1] + red[1][2] + red[1][3];
  float mu = s * (1.0f / 1024.0f);
  float var = ss * (1.0f / 1024.0f) - mu * mu;
  float rstd = rsqrtf(var + 1e-5f);
  const float4 gv = ((const float4*)g)[threadIdx.x];
  const float4 bv = ((const float4*)bln)[threadIdx.x];
  uint2 o2;
  o2.x = cvtpk((v.x - mu) * rstd * gv.x + bv.x, (v.y - mu) * rstd * gv.y + bv.y);
  o2.y = cvtpk((v.z - mu) * rstd * gv.z + bv.z, (v.w - mu) * rstd * gv.w + bv.w);
  ((uint2*)h2)[base] = o2;
}

// ---------------- fused: out += q1  (bias+x1 already in out) ----------------
__global__ __launch_bounds__(256) void fused_add_kernel(
    float* __restrict__ out, const float* __restrict__ q1, int n4) {
  for (int i = blockIdx.x * 256 + threadIdx.x; i < n4; i += gridDim.x * 256) {
    float4 a = ((const float4*)out)[i];
    float4 c = ((const float4*)q1)[i];
    float4 v;
    v.x = a.x + c.x;
    v.y = a.y + c.y;
    v.z = a.z + c.z;
    v.w = a.w + c.w;
    ((float4*)out)[i] = v;
  }
}

// ---------------- 256x256 GEMM, BK=64, 4-phase counted-vmcnt schedule -------
// (round-11 configuration — session best)
// EPI 2: bf16 = gelu(acc+bias)
// EPI 4: split-K fused: kq==0 -> out0 = acc+bias+res (f32); kq==1 -> out1 = acc
// EPI 6: qkv with fused V-transpose: cols < 2048 -> bf16 qkvb; cols >= 2048
//        -> vt[bh][d][t] (j-loop rows are consecutive t -> one ushort4 store).
template <int EPI>
__global__ __launch_bounds__(512, 1) void gemm256_kernel(
    const bf16* __restrict__ A, const bf16* __restrict__ Bt,
    const float* __restrict__ bias, const float* __restrict__ res,
    float* __restrict__ out0, float* __restrict__ out1,
    void* __restrict__ outv, bf16* __restrict__ vtx, int M, int N, int Kfull,
    int Ksub, int ntiles) {
  __shared__ short As[2][256 * 64];
  __shared__ short Bs[2][256 * 64];
  const int tid = threadIdx.x;
  const int lane = tid & 63, wid = tid >> 6;
  const int wr = wid >> 2, wc = wid & 3;

  const int nwg = gridDim.x;
  const int flat = blockIdx.x;
  const int sw = (flat & 7) * (nwg >> 3) + (flat >> 3);  // bijective, nwg%8==0
  const int kq = sw / ntiles;
  const int tile = sw % ntiles;
  const int gy = M >> 8;
  const int bcol = tile / gy, brow = tile % gy;
  const int koff = kq * Ksub;
  const int nk = Ksub >> 6;

  const int srow = tid >> 3;
  const int schs = (tid & 7) ^ ((srow >> 1) & 7);  // pair-swizzle

  const bf16* gA[4];
  const bf16* gB[4];
  int dstL[4];
#pragma unroll
  for (int r = 0; r < 4; r++) {
    gA[r] = A + (size_t)(brow * 256 + r * 64 + srow) * Kfull + koff + schs * 8;
    gB[r] = Bt + (size_t)(bcol * 256 + r * 64 + srow) * Kfull + koff + schs * 8;
    dstL[r] = (r * 64 + wid * 8) * 64;
  }

  auto stA_half = [&](int kt, int buf, int hf) {
#pragma unroll
    for (int rr = 0; rr < 2; rr++) {
      const int r = hf * 2 + rr;
      __builtin_amdgcn_global_load_lds(
          (const __attribute__((address_space(1))) unsigned int*)(gA[r] +
                                                                  kt * 64),
          (__attribute__((address_space(3))) unsigned int*)&As[buf][dstL[r]],
          16, 0, 0);
    }
  };
  auto stB_half = [&](int kt, int buf, int hf) {
#pragma unroll
    for (int rr = 0; rr < 2; rr++) {
      const int r = hf * 2 + rr;
      __builtin_amdgcn_global_load_lds(
          (const __attribute__((address_space(1))) unsigned int*)(gB[r] +
                                                                  kt * 64),
          (__attribute__((address_space(3))) unsigned int*)&Bs[buf][dstL[r]],
          16, 0, 0);
    }
  };

  int ofA[2][4][2], ofB[2][2][2];
#pragma unroll
  for (int qm = 0; qm < 2; qm++)
#pragma unroll
    for (int mm = 0; mm < 4; mm++)
#pragma unroll
      for (int ks = 0; ks < 2; ks++) {
        int row = wr * 128 + qm * 64 + mm * 16 + (lane & 15);
        int ch = (ks * 4 + (lane >> 4)) ^ ((row >> 1) & 7);
        ofA[qm][mm][ks] = row * 64 + ch * 8;
      }
#pragma unroll
  for (int qn = 0; qn < 2; qn++)
#pragma unroll
    for (int nn = 0; nn < 2; nn++)
#pragma unroll
      for (int ks = 0; ks < 2; ks++) {
        int row = wc * 64 + qn * 32 + nn * 16 + (lane & 15);
        int ch = (ks * 4 + (lane >> 4)) ^ ((row >> 1) & 7);
        ofB[qn][nn][ks] = row * 64 + ch * 8;
      }

  f32x4 acc[8][4] = {};
  bf16x8 af[4][2], bf0[2][2], bf1[2][2];

  stA_half(0, 0, 0);
  stA_half(0, 0, 1);
  stB_half(0, 0, 0);
  stB_half(0, 0, 1);
  if (nk > 1) {
    stB_half(1, 1, 0);
    stB_half(1, 1, 1);
    asm volatile("s_waitcnt vmcnt(4)" ::: "memory");
  } else {
    asm volatile("s_waitcnt vmcnt(0)" ::: "memory");
  }
  __builtin_amdgcn_s_barrier();

  for (int t = 0; t < nk; t++) {
    const int cur = t & 1, nxt = cur ^ 1;
    const short* Ac = As[cur];
    const short* Bc = Bs[cur];
    // ---- P1: quad (0,0)
#pragma unroll
    for (int mm = 0; mm < 4; mm++)
#pragma unroll
      for (int ks = 0; ks < 2; ks++)
        af[mm][ks] = *(const bf16x8*)&Ac[ofA[0][mm][ks]];
#pragma unroll
    for (int nn = 0; nn < 2; nn++)
#pragma unroll
      for (int ks = 0; ks < 2; ks++)
        bf0[nn][ks] = *(const bf16x8*)&Bc[ofB[0][nn][ks]];
    if (t + 1 < nk) stA_half(t + 1, nxt, 0);
    __builtin_amdgcn_s_barrier();
    asm volatile("s_waitcnt lgkmcnt(0)" ::: "memory");
    __builtin_amdgcn_sched_barrier(0);
    __builtin_amdgcn_s_setprio(1);
#pragma unroll
    for (int mm = 0; mm < 4; mm++)
#pragma unroll
      for (int nn = 0; nn < 2; nn++)
#pragma unroll
        for (int ks = 0; ks < 2; ks++)
          acc[mm][nn] = __builtin_amdgcn_mfma_f32_16x16x32_bf16(
              af[mm][ks], bf0[nn][ks], acc[mm][nn], 0, 0, 0);
    __builtin_amdgcn_s_setprio(0);
    __builtin_amdgcn_s_barrier();
    // ---- P2: quad (0,1)
#pragma unroll
    for (int nn = 0; nn < 2; nn++)
#pragma unroll
      for (int ks = 0; ks < 2; ks++)
        bf1[nn][ks] = *(const bf16x8*)&Bc[ofB[1][nn][ks]];
    if (t + 1 < nk) stA_half(t + 1, nxt, 1);
    __builtin_amdgcn_s_barrier();
    asm volatile("s_waitcnt lgkmcnt(0)" ::: "memory");
    __builtin_amdgcn_sched_barrier(0);
    __builtin_amdgcn_s_setprio(1);
#pragma unroll
    for (int mm = 0; mm < 4; mm++)
#pragma unroll
      for (int nn = 0; nn < 2; nn++)
#pragma unroll
        for (int ks = 0; ks < 2; ks++)
          acc[mm][2 + nn] = __builtin_amdgcn_mfma_f32_16x16x32_bf16(
              af[mm][ks], bf1[nn][ks], acc[mm][2 + nn], 0, 0, 0);
    __builtin_amdgcn_s_setprio(0);
    __builtin_amdgcn_s_barrier();
    // ---- P3: quad (1,1)
#pragma unroll
    for (int mm = 0; mm < 4; mm++)
#pragma unroll
      for (int ks = 0; ks < 2; ks++)
        af[mm][ks] = *(const bf16x8*)&Ac[ofA[1][mm][ks]];
    if (t + 2 < nk) stB_half(t + 2, cur, 0);
    __builtin_amdgcn_s_barrier();
    asm volatile("s_waitcnt lgkmcnt(0)" ::: "memory");
    __builtin_amdgcn_sched_barrier(0);
    __builtin_amdgcn_s_setprio(1);
#pragma unroll
    for (int mm = 0; mm < 4; mm++)
#pragma unroll
      for (int nn = 0; nn < 2; nn++)
#pragma unroll
        for (int ks = 0; ks < 2; ks++)
          acc[4 + mm][2 + nn] = __builtin_amdgcn_mfma_f32_16x16x32_bf16(
              af[mm][ks], bf1[nn][ks], acc[4 + mm][2 + nn], 0, 0, 0);
    __builtin_amdgcn_s_setprio(0);
    __builtin_amdgcn_s_barrier();
    // ---- P4: quad (1,0) — register-only
    if (t + 2 < nk) stB_half(t + 2, cur, 1);
    __builtin_amdgcn_s_setprio(1);
#pragma unroll
    for (int mm = 0; mm < 4; mm++)
#pragma unroll
      for (int nn = 0; nn < 2; nn++)
#pragma unroll
        for (int ks = 0; ks < 2; ks++)
          acc[4 + mm][nn] = __builtin_amdgcn_mfma_f32_16x16x32_bf16(
              af[mm][ks], bf0[nn][ks], acc[4 + mm][nn], 0, 0, 0);
    __builtin_amdgcn_s_setprio(0);
    if (t + 2 < nk)
      asm volatile("s_waitcnt vmcnt(4)" ::: "memory");
    else if (t + 1 < nk)
      asm volatile("s_waitcnt vmcnt(0)" ::: "memory");
    __builtin_amdgcn_s_barrier();
  }

  // epilogue
#pragma unroll
  for (int m = 0; m < 8; m++)
#pragma unroll
    for (int n = 0; n < 4; n++) {
      int gr0 = brow * 256 + wr * 128 + m * 16 + (lane >> 4) * 4;
      int gc = bcol * 256 + wc * 64 + n * 16 + (lane & 15);
      if constexpr (EPI == 4) {
        if (kq == 0) {
          float bia = bias[gc];
#pragma unroll
          for (int j = 0; j < 4; j++) {
            size_t idx = (size_t)(gr0 + j) * N + gc;
            out0[idx] = acc[m][n][j] + bia + res[idx];
          }
        } else {
#pragma unroll
          for (int j = 0; j < 4; j++)
            out1[(size_t)(gr0 + j) * N + gc] = acc[m][n][j];
        }
      } else if constexpr (EPI == 6) {
        float bia = bias[gc];
        if (gc < 2048) {
#pragma unroll
          for (int j = 0; j < 4; j++)
            ((bf16*)outv)[(size_t)(gr0 + j) * N + gc] =
                __float2bfloat16(acc[m][n][j] + bia);
        } else {
          // V column: write transposed to vt[bh][d][t] (t = gr0..gr0+3)
          int local = gc - 2048;
          int hh = local >> 6, dd = local & 63;
          int bb = gr0 >> 11, tt = gr0 & 2047;
          uint2 o2;
          o2.x = cvtpk(acc[m][n][0] + bia, acc[m][n][1] + bia);
          o2.y = cvtpk(acc[m][n][2] + bia, acc[m][n][3] + bia);
          *(uint2*)&vtx[((size_t)(bb * 16 + hh) * 64 + dd) * 2048 + tt] = o2;
        }
      } else {
        float bia = bias[gc];
#pragma unroll
        for (int j = 0; j < 4; j++) {
          float v = acc[m][n][j] + bia;
          size_t idx = (size_t)(gr0 + j) * N + gc;
          float u = 0.7978845608028654f * (v + 0.044715f * v * v * v);
          float t2 = exp2_fast(u * (2.0f * LOG2E));
          float th = 1.0f - 2.0f / (t2 + 1.0f);
          ((bf16*)outv)[idx] = __float2bfloat16(0.5f * v * (1.0f + th));
        }
      }
    }
}

// ---------------- Flash attention: swapped-QK^T 32x32, double-buffered ------
// Round-6 proven structure + cvt_pk/exp surgery; pair-swizzle (row>>1)&7.
__global__ __launch_bounds__(256) void attn_kernel(
    const bf16* __restrict__ qkv, const bf16* __restrict__ vt,
    bf16* __restrict__ attn) {
  const int bh = blockIdx.x;
  const int qt = 15 - blockIdx.y;  // heavy tiles dispatch first
  const int b = bh >> 4, h = bh & 15;
  const int tid = threadIdx.x, w = tid >> 6, lane = tid & 63;
  const int col = lane & 31;
  const int hi = lane >> 5;

  __shared__ short Kl[2][64 * 64];
  __shared__ short Vl[2][64 * 64];

  const int qbase = qt * 128 + w * 32;
  const int qglob = qbase + col;
  const size_t qrow = (size_t)(b * 2048 + qglob);

  // Q fragments, scale 0.125*LOG2E folded in; packed via cvt_pk
  union U8 { unsigned u[4]; bf16x8 v; };
  U8 qf[4];
#pragma unroll
  for (int dks = 0; dks < 4; dks++) {
    bf16x8 raw =
        *(const bf16x8*)&qkv[qrow * 3072 + h * 64 + dks * 16 + hi * 8];
#pragma unroll
    for (int p = 0; p < 4; p++)
      qf[dks].u[p] = cvtpk(b2f(raw[2 * p]) * (0.125f * LOG2E),
                           b2f(raw[2 * p + 1]) * (0.125f * LOG2E));
  }

  auto stage = [&](int kt, int buf) {
    const int kv0s = kt * 64;
#pragma unroll
    for (int j = 0; j < 2; j++) {
      int c = (j * 4 + w) * 64 + lane;
      int row = c >> 3;
      int sw8 = ((c & 7) ^ ((row >> 1) & 7)) * 8;  // pair-swizzle
      const bf16* gk =
          qkv + (size_t)(b * 2048 + kv0s + row) * 3072 + 1024 + h * 64 + sw8;
      __builtin_amdgcn_global_load_lds(
          (const __attribute__((address_space(1))) unsigned int*)gk,
          (__attribute__((address_space(3))) unsigned int*)(
              &Kl[buf][(j * 4 + w) * 512]),
          16, 0, 0);
      const bf16* gv = vt + (size_t)(bh * 64 + row) * 2048 + kv0s + sw8;
      __builtin_amdgcn_global_load_lds(
          (const __attribute__((address_space(1))) unsigned int*)gv,
          (__attribute__((address_space(3))) unsigned int*)(
              &Vl[buf][(j * 4 + w) * 512]),
          16, 0, 0);
    }
  };

  f32x16 ot[2] = {};
  float m = -1e30f, l = 0.0f;

  const int ktend = qt * 2 + 1;
  stage(0, 0);
  for (int kt = 0; kt <= ktend; kt++) {
    const int kv0 = kt * 64;
    const int cur = kt & 1;
    if (kt < ktend) {
      stage(kt + 1, cur ^ 1);
      asm volatile("s_waitcnt vmcnt(4)" ::: "memory");
    } else {
      asm volatile("s_waitcnt vmcnt(0)" ::: "memory");
    }
    __builtin_amdgcn_s_barrier();

    if (kv0 <= qbase + 31) {
      f32x16 st[2] = {};
#pragma unroll
      for (int s = 0; s < 2; s++) {
        int kvrow = s * 32 + col;
        int swz = (kvrow >> 1) & 7;
#pragma unroll
        for (int dks = 0; dks < 4; dks++) {
          int ch = (dks * 2 + hi) ^ swz;
          bf16x8 kf = *(const bf16x8*)&Kl[cur][kvrow * 64 + ch * 8];
          st[s] = __builtin_amdgcn_mfma_f32_32x32x16_bf16(kf, qf[dks].v,
                                                          st[s], 0, 0, 0);
        }
      }
      if (kv0 + 63 > qbase) {
#pragma unroll
        for (int s = 0; s < 2; s++)
#pragma unroll
          for (int r = 0; r < 16; r++) {
            int kv = kv0 + s * 32 + (r & 3) + 8 * (r >> 2) + 4 * hi;
            if (kv > qglob) st[s][r] = -1e30f;
          }
      }
      // tree max (depth 5)
      float vm[16];
#pragma unroll
      for (int i = 0; i < 16; i++) vm[i] = fmaxf(st[0][i], st[1][i]);
#pragma unroll
      for (int w2 = 8; w2 >= 1; w2 >>= 1)
#pragma unroll
        for (int i = 0; i < w2; i++) vm[i] = fmaxf(vm[i], vm[i + w2]);
      float pmax = fmaxf(vm[0], __shfl_xor(vm[0], 32));
      // T13 defer-rescale (log2 units, THR=8)
      if (!__all(pmax - m <= 8.0f)) {
        float mnew = fmaxf(m, pmax);
        float corr = exp2_fast(m - mnew);
        m = mnew;
        l *= corr;
#pragma unroll
        for (int s = 0; s < 2; s++)
#pragma unroll
          for (int r = 0; r < 16; r++) ot[s][r] *= corr;
      }
#pragma unroll
      for (int s = 0; s < 2; s++)
#pragma unroll
        for (int r = 0; r < 16; r++) st[s][r] = exp2_fast(st[s][r] - m);
      // tree sum
      float vs[16];
#pragma unroll
      for (int i = 0; i < 16; i++) vs[i] = st[0][i] + st[1][i];
#pragma unroll
      for (int w2 = 8; w2 >= 1; w2 >>= 1)
#pragma unroll
        for (int i = 0; i < w2; i++) vs[i] += vs[i + w2];
      l += vs[0] + __shfl_xor(vs[0], 32);

      // P^T fragments: cvt_pk pairs + shfl_xor(32); PV
#pragma unroll
      for (int sub = 0; sub < 2; sub++) {
#pragma unroll
        for (int kl = 0; kl < 2; kl++) {
          unsigned A0 = cvtpk(st[sub][kl * 8 + 0], st[sub][kl * 8 + 1]);
          unsigned A1 = cvtpk(st[sub][kl * 8 + 2], st[sub][kl * 8 + 3]);
          unsigned B0 = cvtpk(st[sub][kl * 8 + 4], st[sub][kl * 8 + 5]);
          unsigned B1 = cvtpk(st[sub][kl * 8 + 6], st[sub][kl * 8 + 7]);
          unsigned sA0 = (unsigned)__shfl_xor((int)A0, 32);
          unsigned sA1 = (unsigned)__shfl_xor((int)A1, 32);
          unsigned sB0 = (unsigned)__shfl_xor((int)B0, 32);
          unsigned sB1 = (unsigned)__shfl_xor((int)B1, 32);
          U8 pf;
          pf.u[0] = hi ? sB0 : A0;
          pf.u[1] = hi ? sB1 : A1;
          pf.u[2] = hi ? B0 : sA0;
          pf.u[3] = hi ? B1 : sA1;
          int ks = sub * 2 + kl;
#pragma unroll
          for (int ds = 0; ds < 2; ds++) {
            int drow = ds * 32 + col;
            int ch = (ks * 2 + hi) ^ ((drow >> 1) & 7);
            bf16x8 vf = *(const bf16x8*)&Vl[cur][drow * 64 + ch * 8];
            ot[ds] = __builtin_amdgcn_mfma_f32_32x32x16_bf16(vf, pf.v, ot[ds],
                                                             0, 0, 0);
          }
        }
      }
    }
    __builtin_amdgcn_s_barrier();
  }

  float rl = 1.0f / l;
#pragma unroll
  for (int ds = 0; ds < 2; ds++)
#pragma unroll
    for (int j = 0; j < 4; j++) {
      uint2 o2;
      o2.x = cvtpk(ot[ds][4 * j + 0] * rl, ot[ds][4 * j + 1] * rl);
      o2.y = cvtpk(ot[ds][4 * j + 2] * rl, ot[ds][4 * j + 3] * rl);
      *(uint2*)&attn[qrow * 1024 + h * 64 + 32 * ds + 8 * j + 4 * hi] = o2;
    }
}

// ---------------- host-side orchestration -----------------------------------
extern "C" void kernel_launch(void* const* d_in, const int* in_sizes, int n_in,
                              void* d_out, int out_size, void* d_ws,
                              size_t ws_size, hipStream_t stream) {
  (void)in_sizes; (void)n_in; (void)out_size; (void)ws_size;
  const float* x      = (const float*)d_in[0];
  const float* ln1_g  = (const float*)d_in[1];
  const float* ln1_b  = (const float*)d_in[2];
  const float* w_qkv  = (const float*)d_in[3];
  const float* b_qkv  = (const float*)d_in[4];
  const float* w_o    = (const float*)d_in[5];
  const float* b_o    = (const float*)d_in[6];
  const float* ln2_g  = (const float*)d_in[7];
  const float* ln2_b  = (const float*)d_in[8];
  const float* w_fc   = (const float*)d_in[9];
  const float* b_fc   = (const float*)d_in[10];
  const float* w_proj = (const float*)d_in[11];
  const float* b_proj = (const float*)d_in[12];
  float* out = (float*)d_out;

  char* ws = (char*)d_ws;
  const size_t MB = 1048576;
  float* x1     = (float*)(ws + 0);          // 32 MB f32 [8192][1024]
  bf16* slotA   = (bf16*)(ws + 32 * MB);     // 16 MB  h / attn / h2
  bf16* wt_qkv  = (bf16*)(ws + 48 * MB);     //  6 MB
  bf16* wt_o    = (bf16*)(ws + 54 * MB);     //  2 MB
  bf16* wt_fc   = (bf16*)(ws + 56 * MB);     //  8 MB
  bf16* wt_proj = (bf16*)(ws + 64 * MB);     //  8 MB
  bf16* qkvb    = (bf16*)(ws + 72 * MB);     // 48 MB [8192][3072] (V cols unused)
  bf16* vtb     = (bf16*)(ws + 120 * MB);    // 16 MB
  float* p0     = (float*)(ws + 72 * MB);    // 32 MB (over qkvb, dead)
  float* p1     = (float*)(ws + 104 * MB);   // 32 MB (over qkvb/vtb, dead)
  bf16* gbuf    = (bf16*)(ws + 72 * MB);     // 64 MB (over p0/p1, dead)
  float* q1     = (float*)(ws + 32 * MB);    // 32 MB (over slotA+wt_*, dead)

  dim3 blk(256);
  transpose_cast_kernel<<<dim3(3072 / 32, 1024 / 32), blk, 0, stream>>>(
      w_qkv, wt_qkv, 1024, 3072);
  transpose_cast_kernel<<<dim3(1024 / 32, 1024 / 32), blk, 0, stream>>>(
      w_o, wt_o, 1024, 1024);
  transpose_cast_kernel<<<dim3(4096 / 32, 1024 / 32), blk, 0, stream>>>(
      w_fc, wt_fc, 1024, 4096);
  transpose_cast_kernel<<<dim3(1024 / 32, 4096 / 32), blk, 0, stream>>>(
      w_proj, wt_proj, 4096, 1024);

  ln_kernel<<<8192, blk, 0, stream>>>(x, ln1_g, ln1_b, slotA);
  // qkv with fused V-transpose (Q/K -> qkvb, V -> vtb)
  gemm256_kernel<6><<<dim3(384), dim3(512), 0, stream>>>(
      slotA, wt_qkv, b_qkv, nullptr, nullptr, nullptr, qkvb, vtb, 8192, 3072,
      1024, 1024, 384);
  attn_kernel<<<dim3(64, 16), blk, 0, stream>>>(qkvb, vtb, slotA);
  gemm256_kernel<4><<<dim3(256), dim3(512), 0, stream>>>(
      slotA, wt_o, b_o, x, p0, p1, nullptr, nullptr, 8192, 1024, 1024, 512,
      128);
  fused_ln_kernel<<<8192, blk, 0, stream>>>(p0, p1, ln2_g, ln2_b, x1, slotA);
  gemm256_kernel<2><<<dim3(512), dim3(512), 0, stream>>>(
      slotA, wt_fc, b_fc, nullptr, nullptr, nullptr, gbuf, nullptr, 8192, 4096,
      1024, 1024, 512);
  gemm256_kernel<4><<<dim3(256), dim3(512), 0, stream>>>(
      gbuf, wt_proj, b_proj, x1, out, q1, nullptr, nullptr, 8192, 1024, 4096,
      2048, 128);
  fused_add_kernel<<<dim3(2048), blk, 0, stream>>>(out, q1, 2097152);
}

// Round 20
// 402.712 us; speedup vs baseline: 1.0185x; 1.0185x over previous
//
#include <hip/hip_runtime.h>
#include <hip/hip_bf16.h>

using bf16 = __hip_bfloat16;
typedef __attribute__((ext_vector_type(8))) short bf16x8;
typedef __attribute__((ext_vector_type(4))) float f32x4;
typedef __attribute__((ext_vector_type(16))) float f32x16;

#define LOG2E 1.4426950408889634f

__device__ inline short f2b(float f) {
  __hip_bfloat16 h = __float2bfloat16(f);
  return *reinterpret_cast<short*>(&h);
}
__device__ inline float b2f(short s) {
  unsigned int u = ((unsigned int)(unsigned short)s) << 16;
  float f;
  __builtin_memcpy(&f, &u, 4);
  return f;
}
// single-instruction packed f32x2 -> bf16x2 (RNE), lo = a, hi = b
__device__ inline unsigned cvtpk(float a, float b) {
  unsigned r;
  asm("v_cvt_pk_bf16_f32 %0, %1, %2" : "=v"(r) : "v"(a), "v"(b));
  return r;
}
// raw v_exp_f32: D = 2^S0 (no libm range checks)
__device__ inline float exp2_fast(float x) {
  float r;
  asm("v_exp_f32 %0, %1" : "=v"(r) : "v"(x));
  return r;
}

// ---------------- weight transpose + cast: in[K][N] f32 -> out[N][K] bf16 ----
__global__ __launch_bounds__(256) void transpose_cast_kernel(
    const float* __restrict__ in, bf16* __restrict__ out, int K, int N) {
  __shared__ float tile[32][33];
  int tx = threadIdx.x & 31;
  int ty = threadIdx.x >> 5;
  int n0 = blockIdx.x * 32, k0 = blockIdx.y * 32;
#pragma unroll
  for (int i = 0; i < 4; i++)
    tile[ty + i * 8][tx] = in[(size_t)(k0 + ty + i * 8) * N + n0 + tx];
  __syncthreads();
#pragma unroll
  for (int i = 0; i < 4; i++)
    out[(size_t)(n0 + ty + i * 8) * K + k0 + tx] =
        __float2bfloat16(tile[tx][ty + i * 8]);
}

// ---------------- V transpose: vt[bh][d][t] ---------------------------------
__global__ __launch_bounds__(256) void transpose_v_kernel(
    const bf16* __restrict__ qkv, bf16* __restrict__ vt) {
  __shared__ short tile[64][66];
  const int bh = blockIdx.y;
  const int b = bh >> 4, h = bh & 15;
  const int t0 = blockIdx.x * 64;
  const int tid = threadIdx.x;
  const int r = tid >> 3, c8 = (tid & 7) * 8;
#pragma unroll
  for (int p = 0; p < 2; p++) {
    int t = r + p * 32;
    bf16x8 v = *(const bf16x8*)&qkv[(size_t)(b * 2048 + t0 + t) * 3072 + 2048 +
                                    h * 64 + c8];
#pragma unroll
    for (int i = 0; i < 8; i++) tile[t][c8 + i] = v[i];
  }
  __syncthreads();
#pragma unroll
  for (int p = 0; p < 2; p++) {
    int d = r + p * 32;
    int tt = c8;
    bf16x8 o;
#pragma unroll
    for (int i = 0; i < 8; i++) o[i] = tile[tt + i][d];
    *(bf16x8*)&vt[(size_t)(bh * 64 + d) * 2048 + t0 + tt] = o;
  }
}

// ---------------- LayerNorm (LN1): f32 in -> bf16 out -----------------------
__global__ __launch_bounds__(256) void ln_kernel(
    const float* __restrict__ x, const float* __restrict__ g,
    const float* __restrict__ b, bf16* __restrict__ out) {
  int row = blockIdx.x;
  const float4 v = ((const float4*)(x + (size_t)row * 1024))[threadIdx.x];
  float s = v.x + v.y + v.z + v.w;
  float ss = v.x * v.x + v.y * v.y + v.z * v.z + v.w * v.w;
#pragma unroll
  for (int off = 1; off < 64; off <<= 1) {
    s += __shfl_xor(s, off);
    ss += __shfl_xor(ss, off);
  }
  __shared__ float red[2][4];
  int w = threadIdx.x >> 6, lane = threadIdx.x & 63;
  if (lane == 0) { red[0][w] = s; red[1][w] = ss; }
  __syncthreads();
  s = red[0][0] + red[0][1] + red[0][2] + red[0][3];
  ss = red[1][0] + red[1][1] + red[1][2] + red[1][3];
  float mu = s * (1.0f / 1024.0f);
  float var = ss * (1.0f / 1024.0f) - mu * mu;
  float rstd = rsqrtf(var + 1e-5f);
  const float4 gv = ((const float4*)g)[threadIdx.x];
  const float4 bv = ((const float4*)b)[threadIdx.x];
  uint2 o2;
  o2.x = cvtpk((v.x - mu) * rstd * gv.x + bv.x, (v.y - mu) * rstd * gv.y + bv.y);
  o2.y = cvtpk((v.z - mu) * rstd * gv.z + bv.z, (v.w - mu) * rstd * gv.w + bv.w);
  ((uint2*)out)[(size_t)row * 256 + threadIdx.x] = o2;
}

// ---------------- fused: x1 = p0+p1 ; h2 = LN2(x1)  (bias+res already in p0)
__global__ __launch_bounds__(256) void fused_ln_kernel(
    const float* __restrict__ p0, const float* __restrict__ p1,
    const float* __restrict__ g, const float* __restrict__ bln,
    float* __restrict__ x1, bf16* __restrict__ h2) {
  int row = blockIdx.x;
  size_t base = (size_t)row * 256 + threadIdx.x;
  float4 a = ((const float4*)p0)[base];
  float4 c = ((const float4*)p1)[base];
  float4 v;
  v.x = a.x + c.x;
  v.y = a.y + c.y;
  v.z = a.z + c.z;
  v.w = a.w + c.w;
  ((float4*)x1)[base] = v;
  float s = v.x + v.y + v.z + v.w;
  float ss = v.x * v.x + v.y * v.y + v.z * v.z + v.w * v.w;
#pragma unroll
  for (int off = 1; off < 64; off <<= 1) {
    s += __shfl_xor(s, off);
    ss += __shfl_xor(ss, off);
  }
  __shared__ float red[2][4];
  int w = threadIdx.x >> 6, lane = threadIdx.x & 63;
  if (lane == 0) { red[0][w] = s; red[1][w] = ss; }
  __syncthreads();
  s = red[0][0] + red[0][1] + red[0][2] + red[0][3];
  ss = red[1][0] + red[1][1] + red[1][2] + red[1][3];
  float mu = s * (1.0f / 1024.0f);
  float var = ss * (1.0f / 1024.0f) - mu * mu;
  float rstd = rsqrtf(var + 1e-5f);
  const float4 gv = ((const float4*)g)[threadIdx.x];
  const float4 bv = ((const float4*)bln)[threadIdx.x];
  uint2 o2;
  o2.x = cvtpk((v.x - mu) * rstd * gv.x + bv.x, (v.y - mu) * rstd * gv.y + bv.y);
  o2.y = cvtpk((v.z - mu) * rstd * gv.z + bv.z, (v.w - mu) * rstd * gv.w + bv.w);
  ((uint2*)h2)[base] = o2;
}

// ---------------- fused: out += q1  (bias+x1 already in out) ----------------
__global__ __launch_bounds__(256) void fused_add_kernel(
    float* __restrict__ out, const float* __restrict__ q1, int n4) {
  for (int i = blockIdx.x * 256 + threadIdx.x; i < n4; i += gridDim.x * 256) {
    float4 a = ((const float4*)out)[i];
    float4 c = ((const float4*)q1)[i];
    float4 v;
    v.x = a.x + c.x;
    v.y = a.y + c.y;
    v.z = a.z + c.z;
    v.w = a.w + c.w;
    ((float4*)out)[i] = v;
  }
}

// ---------------- 256x256 GEMM, BK=64, 4-phase counted-vmcnt schedule -------
// (round-11/12/18 configuration — session best band 403-407 us)
// EPI 0: bf16 = acc+bias ; EPI 2: bf16 = gelu(acc+bias)
// EPI 4: split-K fused: kq==0 -> out0 = acc+bias+res (f32); kq==1 -> out1 = acc
template <int EPI>
__global__ __launch_bounds__(512, 1) void gemm256_kernel(
    const bf16* __restrict__ A, const bf16* __restrict__ Bt,
    const float* __restrict__ bias, const float* __restrict__ res,
    float* __restrict__ out0, float* __restrict__ out1,
    void* __restrict__ outv, int M, int N, int Kfull, int Ksub, int ntiles) {
  __shared__ short As[2][256 * 64];
  __shared__ short Bs[2][256 * 64];
  const int tid = threadIdx.x;
  const int lane = tid & 63, wid = tid >> 6;
  const int wr = wid >> 2, wc = wid & 3;

  const int nwg = gridDim.x;
  const int flat = blockIdx.x;
  const int sw = (flat & 7) * (nwg >> 3) + (flat >> 3);  // bijective, nwg%8==0
  const int kq = sw / ntiles;
  const int tile = sw % ntiles;
  const int gy = M >> 8;
  const int bcol = tile / gy, brow = tile % gy;
  const int koff = kq * Ksub;
  const int nk = Ksub >> 6;

  const int srow = tid >> 3;
  const int schs = (tid & 7) ^ ((srow >> 1) & 7);  // pair-swizzle

  const bf16* gA[4];
  const bf16* gB[4];
  int dstL[4];
#pragma unroll
  for (int r = 0; r < 4; r++) {
    gA[r] = A + (size_t)(brow * 256 + r * 64 + srow) * Kfull + koff + schs * 8;
    gB[r] = Bt + (size_t)(bcol * 256 + r * 64 + srow) * Kfull + koff + schs * 8;
    dstL[r] = (r * 64 + wid * 8) * 64;
  }

  auto stA_half = [&](int kt, int buf, int hf) {
#pragma unroll
    for (int rr = 0; rr < 2; rr++) {
      const int r = hf * 2 + rr;
      __builtin_amdgcn_global_load_lds(
          (const __attribute__((address_space(1))) unsigned int*)(gA[r] +
                                                                  kt * 64),
          (__attribute__((address_space(3))) unsigned int*)&As[buf][dstL[r]],
          16, 0, 0);
    }
  };
  auto stB_half = [&](int kt, int buf, int hf) {
#pragma unroll
    for (int rr = 0; rr < 2; rr++) {
      const int r = hf * 2 + rr;
      __builtin_amdgcn_global_load_lds(
          (const __attribute__((address_space(1))) unsigned int*)(gB[r] +
                                                                  kt * 64),
          (__attribute__((address_space(3))) unsigned int*)&Bs[buf][dstL[r]],
          16, 0, 0);
    }
  };

  int ofA[2][4][2], ofB[2][2][2];
#pragma unroll
  for (int qm = 0; qm < 2; qm++)
#pragma unroll
    for (int mm = 0; mm < 4; mm++)
#pragma unroll
      for (int ks = 0; ks < 2; ks++) {
        int row = wr * 128 + qm * 64 + mm * 16 + (lane & 15);
        int ch = (ks * 4 + (lane >> 4)) ^ ((row >> 1) & 7);
        ofA[qm][mm][ks] = row * 64 + ch * 8;
      }
#pragma unroll
  for (int qn = 0; qn < 2; qn++)
#pragma unroll
    for (int nn = 0; nn < 2; nn++)
#pragma unroll
      for (int ks = 0; ks < 2; ks++) {
        int row = wc * 64 + qn * 32 + nn * 16 + (lane & 15);
        int ch = (ks * 4 + (lane >> 4)) ^ ((row >> 1) & 7);
        ofB[qn][nn][ks] = row * 64 + ch * 8;
      }

  f32x4 acc[8][4] = {};
  bf16x8 af[4][2], bf0[2][2], bf1[2][2];

  stA_half(0, 0, 0);
  stA_half(0, 0, 1);
  stB_half(0, 0, 0);
  stB_half(0, 0, 1);
  if (nk > 1) {
    stB_half(1, 1, 0);
    stB_half(1, 1, 1);
    asm volatile("s_waitcnt vmcnt(4)" ::: "memory");
  } else {
    asm volatile("s_waitcnt vmcnt(0)" ::: "memory");
  }
  __builtin_amdgcn_s_barrier();

  for (int t = 0; t < nk; t++) {
    const int cur = t & 1, nxt = cur ^ 1;
    const short* Ac = As[cur];
    const short* Bc = Bs[cur];
    // ---- P1: quad (0,0)
#pragma unroll
    for (int mm = 0; mm < 4; mm++)
#pragma unroll
      for (int ks = 0; ks < 2; ks++)
        af[mm][ks] = *(const bf16x8*)&Ac[ofA[0][mm][ks]];
#pragma unroll
    for (int nn = 0; nn < 2; nn++)
#pragma unroll
      for (int ks = 0; ks < 2; ks++)
        bf0[nn][ks] = *(const bf16x8*)&Bc[ofB[0][nn][ks]];
    if (t + 1 < nk) stA_half(t + 1, nxt, 0);
    __builtin_amdgcn_s_barrier();
    asm volatile("s_waitcnt lgkmcnt(0)" ::: "memory");
    __builtin_amdgcn_sched_barrier(0);
    __builtin_amdgcn_s_setprio(1);
#pragma unroll
    for (int mm = 0; mm < 4; mm++)
#pragma unroll
      for (int nn = 0; nn < 2; nn++)
#pragma unroll
        for (int ks = 0; ks < 2; ks++)
          acc[mm][nn] = __builtin_amdgcn_mfma_f32_16x16x32_bf16(
              af[mm][ks], bf0[nn][ks], acc[mm][nn], 0, 0, 0);
    __builtin_amdgcn_s_setprio(0);
    __builtin_amdgcn_s_barrier();
    // ---- P2: quad (0,1)
#pragma unroll
    for (int nn = 0; nn < 2; nn++)
#pragma unroll
      for (int ks = 0; ks < 2; ks++)
        bf1[nn][ks] = *(const bf16x8*)&Bc[ofB[1][nn][ks]];
    if (t + 1 < nk) stA_half(t + 1, nxt, 1);
    __builtin_amdgcn_s_barrier();
    asm volatile("s_waitcnt lgkmcnt(0)" ::: "memory");
    __builtin_amdgcn_sched_barrier(0);
    __builtin_amdgcn_s_setprio(1);
#pragma unroll
    for (int mm = 0; mm < 4; mm++)
#pragma unroll
      for (int nn = 0; nn < 2; nn++)
#pragma unroll
        for (int ks = 0; ks < 2; ks++)
          acc[mm][2 + nn] = __builtin_amdgcn_mfma_f32_16x16x32_bf16(
              af[mm][ks], bf1[nn][ks], acc[mm][2 + nn], 0, 0, 0);
    __builtin_amdgcn_s_setprio(0);
    __builtin_amdgcn_s_barrier();
    // ---- P3: quad (1,1)
#pragma unroll
    for (int mm = 0; mm < 4; mm++)
#pragma unroll
      for (int ks = 0; ks < 2; ks++)
        af[mm][ks] = *(const bf16x8*)&Ac[ofA[1][mm][ks]];
    if (t + 2 < nk) stB_half(t + 2, cur, 0);
    __builtin_amdgcn_s_barrier();
    asm volatile("s_waitcnt lgkmcnt(0)" ::: "memory");
    __builtin_amdgcn_sched_barrier(0);
    __builtin_amdgcn_s_setprio(1);
#pragma unroll
    for (int mm = 0; mm < 4; mm++)
#pragma unroll
      for (int nn = 0; nn < 2; nn++)
#pragma unroll
        for (int ks = 0; ks < 2; ks++)
          acc[4 + mm][2 + nn] = __builtin_amdgcn_mfma_f32_16x16x32_bf16(
              af[mm][ks], bf1[nn][ks], acc[4 + mm][2 + nn], 0, 0, 0);
    __builtin_amdgcn_s_setprio(0);
    __builtin_amdgcn_s_barrier();
    // ---- P4: quad (1,0) — register-only
    if (t + 2 < nk) stB_half(t + 2, cur, 1);
    __builtin_amdgcn_s_setprio(1);
#pragma unroll
    for (int mm = 0; mm < 4; mm++)
#pragma unroll
      for (int nn = 0; nn < 2; nn++)
#pragma unroll
        for (int ks = 0; ks < 2; ks++)
          acc[4 + mm][nn] = __builtin_amdgcn_mfma_f32_16x16x32_bf16(
              af[mm][ks], bf0[nn][ks], acc[4 + mm][nn], 0, 0, 0);
    __builtin_amdgcn_s_setprio(0);
    if (t + 2 < nk)
      asm volatile("s_waitcnt vmcnt(4)" ::: "memory");
    else if (t + 1 < nk)
      asm volatile("s_waitcnt vmcnt(0)" ::: "memory");
    __builtin_amdgcn_s_barrier();
  }

  // epilogue
#pragma unroll
  for (int m = 0; m < 8; m++)
#pragma unroll
    for (int n = 0; n < 4; n++) {
      int gr0 = brow * 256 + wr * 128 + m * 16 + (lane >> 4) * 4;
      int gc = bcol * 256 + wc * 64 + n * 16 + (lane & 15);
      if constexpr (EPI == 4) {
        if (kq == 0) {
          float bia = bias[gc];
#pragma unroll
          for (int j = 0; j < 4; j++) {
            size_t idx = (size_t)(gr0 + j) * N + gc;
            out0[idx] = acc[m][n][j] + bia + res[idx];
          }
        } else {
#pragma unroll
          for (int j = 0; j < 4; j++)
            out1[(size_t)(gr0 + j) * N + gc] = acc[m][n][j];
        }
      } else {
        float bia = bias[gc];
#pragma unroll
        for (int j = 0; j < 4; j++) {
          float v = acc[m][n][j] + bia;
          size_t idx = (size_t)(gr0 + j) * N + gc;
          if constexpr (EPI == 0) {
            ((bf16*)outv)[idx] = __float2bfloat16(v);
          } else {
            float u = 0.7978845608028654f * (v + 0.044715f * v * v * v);
            float t2 = exp2_fast(u * (2.0f * LOG2E));
            float th = 1.0f - 2.0f / (t2 + 1.0f);
            ((bf16*)outv)[idx] = __float2bfloat16(0.5f * v * (1.0f + th));
          }
        }
      }
    }
}

// ---------------- Flash attention: swapped-QK^T 32x32, double-buffered ------
// Round-6 proven structure + cvt_pk/exp surgery; pair-swizzle (row>>1)&7.
__global__ __launch_bounds__(256) void attn_kernel(
    const bf16* __restrict__ qkv, const bf16* __restrict__ vt,
    bf16* __restrict__ attn) {
  const int bh = blockIdx.x;
  const int qt = 15 - blockIdx.y;  // heavy tiles dispatch first
  const int b = bh >> 4, h = bh & 15;
  const int tid = threadIdx.x, w = tid >> 6, lane = tid & 63;
  const int col = lane & 31;
  const int hi = lane >> 5;

  __shared__ short Kl[2][64 * 64];
  __shared__ short Vl[2][64 * 64];

  const int qbase = qt * 128 + w * 32;
  const int qglob = qbase + col;
  const size_t qrow = (size_t)(b * 2048 + qglob);

  // Q fragments, scale 0.125*LOG2E folded in; packed via cvt_pk
  union U8 { unsigned u[4]; bf16x8 v; };
  U8 qf[4];
#pragma unroll
  for (int dks = 0; dks < 4; dks++) {
    bf16x8 raw =
        *(const bf16x8*)&qkv[qrow * 3072 + h * 64 + dks * 16 + hi * 8];
#pragma unroll
    for (int p = 0; p < 4; p++)
      qf[dks].u[p] = cvtpk(b2f(raw[2 * p]) * (0.125f * LOG2E),
                           b2f(raw[2 * p + 1]) * (0.125f * LOG2E));
  }

  auto stage = [&](int kt, int buf) {
    const int kv0s = kt * 64;
#pragma unroll
    for (int j = 0; j < 2; j++) {
      int c = (j * 4 + w) * 64 + lane;
      int row = c >> 3;
      int sw8 = ((c & 7) ^ ((row >> 1) & 7)) * 8;  // pair-swizzle
      const bf16* gk =
          qkv + (size_t)(b * 2048 + kv0s + row) * 3072 + 1024 + h * 64 + sw8;
      __builtin_amdgcn_global_load_lds(
          (const __attribute__((address_space(1))) unsigned int*)gk,
          (__attribute__((address_space(3))) unsigned int*)(
              &Kl[buf][(j * 4 + w) * 512]),
          16, 0, 0);
      const bf16* gv = vt + (size_t)(bh * 64 + row) * 2048 + kv0s + sw8;
      __builtin_amdgcn_global_load_lds(
          (const __attribute__((address_space(1))) unsigned int*)gv,
          (__attribute__((address_space(3))) unsigned int*)(
              &Vl[buf][(j * 4 + w) * 512]),
          16, 0, 0);
    }
  };

  f32x16 ot[2] = {};
  float m = -1e30f, l = 0.0f;

  const int ktend = qt * 2 + 1;
  stage(0, 0);
  for (int kt = 0; kt <= ktend; kt++) {
    const int kv0 = kt * 64;
    const int cur = kt & 1;
    if (kt < ktend) {
      stage(kt + 1, cur ^ 1);
      asm volatile("s_waitcnt vmcnt(4)" ::: "memory");
    } else {
      asm volatile("s_waitcnt vmcnt(0)" ::: "memory");
    }
    __builtin_amdgcn_s_barrier();

    if (kv0 <= qbase + 31) {
      f32x16 st[2] = {};
#pragma unroll
      for (int s = 0; s < 2; s++) {
        int kvrow = s * 32 + col;
        int swz = (kvrow >> 1) & 7;
#pragma unroll
        for (int dks = 0; dks < 4; dks++) {
          int ch = (dks * 2 + hi) ^ swz;
          bf16x8 kf = *(const bf16x8*)&Kl[cur][kvrow * 64 + ch * 8];
          st[s] = __builtin_amdgcn_mfma_f32_32x32x16_bf16(kf, qf[dks].v,
                                                          st[s], 0, 0, 0);
        }
      }
      if (kv0 + 63 > qbase) {
#pragma unroll
        for (int s = 0; s < 2; s++)
#pragma unroll
          for (int r = 0; r < 16; r++) {
            int kv = kv0 + s * 32 + (r & 3) + 8 * (r >> 2) + 4 * hi;
            if (kv > qglob) st[s][r] = -1e30f;
          }
      }
      // tree max (depth 5)
      float vm[16];
#pragma unroll
      for (int i = 0; i < 16; i++) vm[i] = fmaxf(st[0][i], st[1][i]);
#pragma unroll
      for (int w2 = 8; w2 >= 1; w2 >>= 1)
#pragma unroll
        for (int i = 0; i < w2; i++) vm[i] = fmaxf(vm[i], vm[i + w2]);
      float pmax = fmaxf(vm[0], __shfl_xor(vm[0], 32));
      // T13 defer-rescale (log2 units, THR=8)
      if (!__all(pmax - m <= 8.0f)) {
        float mnew = fmaxf(m, pmax);
        float corr = exp2_fast(m - mnew);
        m = mnew;
        l *= corr;
#pragma unroll
        for (int s = 0; s < 2; s++)
#pragma unroll
          for (int r = 0; r < 16; r++) ot[s][r] *= corr;
      }
#pragma unroll
      for (int s = 0; s < 2; s++)
#pragma unroll
        for (int r = 0; r < 16; r++) st[s][r] = exp2_fast(st[s][r] - m);
      // tree sum
      float vs[16];
#pragma unroll
      for (int i = 0; i < 16; i++) vs[i] = st[0][i] + st[1][i];
#pragma unroll
      for (int w2 = 8; w2 >= 1; w2 >>= 1)
#pragma unroll
        for (int i = 0; i < w2; i++) vs[i] += vs[i + w2];
      l += vs[0] + __shfl_xor(vs[0], 32);

      // P^T fragments: cvt_pk pairs + shfl_xor(32); PV
#pragma unroll
      for (int sub = 0; sub < 2; sub++) {
#pragma unroll
        for (int kl = 0; kl < 2; kl++) {
          unsigned A0 = cvtpk(st[sub][kl * 8 + 0], st[sub][kl * 8 + 1]);
          unsigned A1 = cvtpk(st[sub][kl * 8 + 2], st[sub][kl * 8 + 3]);
          unsigned B0 = cvtpk(st[sub][kl * 8 + 4], st[sub][kl * 8 + 5]);
          unsigned B1 = cvtpk(st[sub][kl * 8 + 6], st[sub][kl * 8 + 7]);
          unsigned sA0 = (unsigned)__shfl_xor((int)A0, 32);
          unsigned sA1 = (unsigned)__shfl_xor((int)A1, 32);
          unsigned sB0 = (unsigned)__shfl_xor((int)B0, 32);
          unsigned sB1 = (unsigned)__shfl_xor((int)B1, 32);
          U8 pf;
          pf.u[0] = hi ? sB0 : A0;
          pf.u[1] = hi ? sB1 : A1;
          pf.u[2] = hi ? B0 : sA0;
          pf.u[3] = hi ? B1 : sA1;
          int ks = sub * 2 + kl;
#pragma unroll
          for (int ds = 0; ds < 2; ds++) {
            int drow = ds * 32 + col;
            int ch = (ks * 2 + hi) ^ ((drow >> 1) & 7);
            bf16x8 vf = *(const bf16x8*)&Vl[cur][drow * 64 + ch * 8];
            ot[ds] = __builtin_amdgcn_mfma_f32_32x32x16_bf16(vf, pf.v, ot[ds],
                                                             0, 0, 0);
          }
        }
      }
    }
    __builtin_amdgcn_s_barrier();
  }

  float rl = 1.0f / l;
#pragma unroll
  for (int ds = 0; ds < 2; ds++)
#pragma unroll
    for (int j = 0; j < 4; j++) {
      uint2 o2;
      o2.x = cvtpk(ot[ds][4 * j + 0] * rl, ot[ds][4 * j + 1] * rl);
      o2.y = cvtpk(ot[ds][4 * j + 2] * rl, ot[ds][4 * j + 3] * rl);
      *(uint2*)&attn[qrow * 1024 + h * 64 + 32 * ds + 8 * j + 4 * hi] = o2;
    }
}

// ---------------- host-side orchestration -----------------------------------
extern "C" void kernel_launch(void* const* d_in, const int* in_sizes, int n_in,
                              void* d_out, int out_size, void* d_ws,
                              size_t ws_size, hipStream_t stream) {
  (void)in_sizes; (void)n_in; (void)out_size; (void)ws_size;
  const float* x      = (const float*)d_in[0];
  const float* ln1_g  = (const float*)d_in[1];
  const float* ln1_b  = (const float*)d_in[2];
  const float* w_qkv  = (const float*)d_in[3];
  const float* b_qkv  = (const float*)d_in[4];
  const float* w_o    = (const float*)d_in[5];
  const float* b_o    = (const float*)d_in[6];
  const float* ln2_g  = (const float*)d_in[7];
  const float* ln2_b  = (const float*)d_in[8];
  const float* w_fc   = (const float*)d_in[9];
  const float* b_fc   = (const float*)d_in[10];
  const float* w_proj = (const float*)d_in[11];
  const float* b_proj = (const float*)d_in[12];
  float* out = (float*)d_out;

  char* ws = (char*)d_ws;
  const size_t MB = 1048576;
  float* x1     = (float*)(ws + 0);          // 32 MB f32 [8192][1024]
  bf16* slotA   = (bf16*)(ws + 32 * MB);     // 16 MB  h / attn / h2
  bf16* wt_qkv  = (bf16*)(ws + 48 * MB);     //  6 MB
  bf16* wt_o    = (bf16*)(ws + 54 * MB);     //  2 MB
  bf16* wt_fc   = (bf16*)(ws + 56 * MB);     //  8 MB
  bf16* wt_proj = (bf16*)(ws + 64 * MB);     //  8 MB
  bf16* qkvb    = (bf16*)(ws + 72 * MB);     // 48 MB [8192][3072]
  bf16* vtb     = (bf16*)(ws + 120 * MB);    // 16 MB
  float* p0     = (float*)(ws + 72 * MB);    // 32 MB (over qkvb, dead)
  float* p1     = (float*)(ws + 104 * MB);   // 32 MB (over qkvb/vtb, dead)
  bf16* gbuf    = (bf16*)(ws + 72 * MB);     // 64 MB (over p0/p1, dead)
  float* q1     = (float*)(ws + 32 * MB);    // 32 MB (over slotA+wt_*, dead)

  dim3 blk(256);
  transpose_cast_kernel<<<dim3(3072 / 32, 1024 / 32), blk, 0, stream>>>(
      w_qkv, wt_qkv, 1024, 3072);
  transpose_cast_kernel<<<dim3(1024 / 32, 1024 / 32), blk, 0, stream>>>(
      w_o, wt_o, 1024, 1024);
  transpose_cast_kernel<<<dim3(4096 / 32, 1024 / 32), blk, 0, stream>>>(
      w_fc, wt_fc, 1024, 4096);
  transpose_cast_kernel<<<dim3(1024 / 32, 4096 / 32), blk, 0, stream>>>(
      w_proj, wt_proj, 4096, 1024);

  ln_kernel<<<8192, blk, 0, stream>>>(x, ln1_g, ln1_b, slotA);
  gemm256_kernel<0><<<dim3(384), dim3(512), 0, stream>>>(
      slotA, wt_qkv, b_qkv, nullptr, nullptr, nullptr, qkvb, 8192, 3072, 1024,
      1024, 384);
  transpose_v_kernel<<<dim3(32, 64), blk, 0, stream>>>(qkvb, vtb);
  attn_kernel<<<dim3(64, 16), blk, 0, stream>>>(qkvb, vtb, slotA);
  gemm256_kernel<4><<<dim3(256), dim3(512), 0, stream>>>(
      slotA, wt_o, b_o, x, p0, p1, nullptr, 8192, 1024, 1024, 512, 128);
  fused_ln_kernel<<<8192, blk, 0, stream>>>(p0, p1, ln2_g, ln2_b, x1, slotA);
  gemm256_kernel<2><<<dim3(512), dim3(512), 0, stream>>>(
      slotA, wt_fc, b_fc, nullptr, nullptr, nullptr, gbuf, 8192, 4096, 1024,
      1024, 512);
  gemm256_kernel<4><<<dim3(256), dim3(512), 0, stream>>>(
      gbuf, wt_proj, b_proj, x1, out, q1, nullptr, 8192, 1024, 4096, 2048,
      128);
  fused_add_kernel<<<dim3(2048), blk, 0, stream>>>(out, q1, 2097152);
}